// Round 6
// baseline (419.194 us; speedup 1.0000x reference)
//
#include <hip/hip_runtime.h>
#include <hip/hip_bf16.h>
#include <math.h>

// Problem constants
#define Ln     35
#define CINn   21
#define CINP   24        // padded CIN (shorts per padded row; 48B rows -> 16B-aligned reads)
#define Fn     128
#define Kn     9
#define Hn     64
#define GB     16        // batch rows per block
#define SEQ_STRIDE 1064  // 44 rows*24 + 8 slack (shorts); row 43+slack reads stay in bounds
#define TILE_STRIDE 136  // 128 + 8 pad (shorts)
#define YP_STRIDE 136    // floats per l in s_yp: 8 waves*16 batch + 8 pad (bank decorrelate)

typedef __attribute__((ext_vector_type(8))) short short8;
typedef __attribute__((ext_vector_type(4))) float f32x4;

static __device__ __forceinline__ unsigned short bf16bits(float f) {
    __hip_bfloat16 h = __float2bfloat16(f);
    return *(unsigned short*)&h;
}

// f32 lane-row (16-lane) sum via DPP rotate-accumulate: VALU pipe, zero LDS traffic.
// row_ror:N dpp_ctrl = 0x120|N. After ror 8,4,2,1 every lane holds the row total.
// (numerically validated in round 4/5; replaces 4x ds_swizzle per value)
template <int CTRL>
static __device__ __forceinline__ float dpp_add(float v) {
    int r = __builtin_amdgcn_update_dpp(0, __builtin_bit_cast(int, v),
                                        CTRL, 0xF, 0xF, true);
    return v + __builtin_bit_cast(float, r);
}
static __device__ __forceinline__ float row_sum16(float v) {
    v = dpp_add<0x128>(v);   // ror 8
    v = dpp_add<0x124>(v);   // ror 4
    v = dpp_add<0x122>(v);   // ror 2
    v = dpp_add<0x121>(v);   // ror 1
    return v;
}

// ---------------- single fused kernel: 16 batch rows / block, 512 threads ----------------
// 8 waves/block; wave w owns conv f-tile [16w,16w+16) and MLP n-tile [16w,16w+16)
// (n<64 = n-head, n>=64 = c-head).
// NOTE (rounds 1-4 lesson): this uniform 18-stage loop is the only structure verified
// spill-free (WRITE_SIZE == output, 128 KiB). Do not peel regions or add branches
// around the barrier without re-checking WRITE_SIZE.
// Round-6 delta (pair-shared conv reads): conv is per-ROW K=32 MFMA instead of
// per-l K=224 chain. Stage (l0,l1) reads padded rows l0..l0+9 ONCE each (10 b128
// instead of 14) and feeds both accumulators: row l0+d -> c0 += W[d]*x, c1 += W[d-1]*x.
// The 32-wide row read spills 8 shorts into the next row; those lanes multiply
// against zero-padded taps (wb2[k] has c>=21 zeroed), so the result is unchanged.
__global__ __launch_bounds__(512, 4) void fused_kernel(
    const float* __restrict__ seq,    const int*   __restrict__ plen_arr,
    const float* __restrict__ conv_w, const float* __restrict__ conv_b,
    const float* __restrict__ n_w1,   const float* __restrict__ n_b1,
    const float* __restrict__ n_w2,   const float* __restrict__ n_b2,
    const float* __restrict__ c_w1,   const float* __restrict__ c_b1,
    const float* __restrict__ c_w2,   const float* __restrict__ c_b2,
    const float* __restrict__ navg_w, const float* __restrict__ navg_b,
    const float* __restrict__ cavg_w, const float* __restrict__ cavg_b,
    const float* __restrict__ out_w,  const float* __restrict__ out_b,
    float* __restrict__ out)
{
    __shared__ __align__(16) unsigned short s_seq[GB * SEQ_STRIDE];      // 34048 B
    __shared__ __align__(16) unsigned short s_tile[4][GB * TILE_STRIDE]; // 17408 B
    __shared__ __align__(16) float s_yp[Ln * YP_STRIDE];                 // 19040 B: [l][wave*16+m]
    // overlays on s_seq (dead after the main loop):
    float* s_y   = (float*)s_seq;            // [2][GB][36] = 1152 floats
    float* s_avg = (float*)s_seq + 1152;     // [8 waves][2][GB] = 256 floats

    const int t    = threadIdx.x;
    const int wave = t >> 6;                 // 0..7
    const int lane = t & 63;
    const int quad = lane >> 4;
    const int col  = lane & 15;
    const int b0   = blockIdx.x * GB;

    // ---- zero-init padded seq (pad rows/channels + slack must be 0) ----
    {
        uint4* p = (uint4*)s_seq;            // 34048/16 = 2128 uint4
        for (int i = t; i < (GB * SEQ_STRIDE) / 8; i += 512)
            p[i] = make_uint4(0u, 0u, 0u, 0u);
    }

    // ---- per-lane loop-invariant weight fragments (single tile per wave) ----
    // conv A-frag per tap k (operand-swapped): A[m=f=16*wave+col][c=quad*8+j], c>=21 -> 0
    // MLP  B-frag: B[k=f][n=16*wave+col]
    short8 wb2[9];
    short8 w1b[4];
    float  cbias[4], b1v, w2v;
    const int head = wave >> 2;              // 0 = n-head (waves 0-3), 1 = c (waves 4-7)
    {
        const int ng = wave * 16 + col;      // conv f (A m-index) AND mlp n-index
        #pragma unroll
        for (int k = 0; k < 9; k++) {
            short8 v;
            #pragma unroll
            for (int j = 0; j < 8; j++) {
                int c = quad * 8 + j;
                float f = (c < CINn) ? conv_w[(k * CINn + c) * Fn + ng] : 0.0f;
                v[j] = (short)bf16bits(f);
            }
            wb2[k] = v;
        }
        const int nl = ng & 63;
        #pragma unroll
        for (int s = 0; s < 4; s++) {
            short8 v;
            #pragma unroll
            for (int j = 0; j < 8; j++) {
                int k = 32 * s + quad * 8 + j;
                float f = head ? c_w1[k * Hn + nl] : n_w1[k * Hn + nl];
                v[j] = (short)bf16bits(f);
            }
            w1b[s] = v;
        }
        #pragma unroll
        for (int r = 0; r < 4; r++)
            cbias[r] = conv_b[wave * 16 + 4 * quad + r];
        b1v = head ? c_b1[nl] : n_b1[nl];
        w2v = head ? c_w2[nl] : n_w2[nl];
    }
    const int plen_lane = plen_arr[b0 + col];   // this lane's batch (=col) plen

    __syncthreads();   // zero-init done before data fill

    // ---- stage seq -> bf16 LDS, rows shifted +4 (SAME pad), c<21 only ----
    for (int i = t; i < GB * Ln * CINn; i += 512) {
        int bi = i / (Ln * CINn), r = i % (Ln * CINn);
        int l = r / CINn, c = r % CINn;
        s_seq[bi * SEQ_STRIDE + (4 + l) * CINP + c] =
            bf16bits(seq[(size_t)(b0 + bi) * (Ln * CINn) + r]);
    }
    __syncthreads();

    float sum_n[4] = {0.f,0.f,0.f,0.f};
    float sum_c[4] = {0.f,0.f,0.f,0.f};

    // ---- main loop: 2 l per stage, 18 stages, 1 barrier each. 4-slot ring:
    // stage i writes slots {2i&3,(2i+1)&3}; WAR on a slot is fenced 1 stage later.
    // l=35 is a computed pad column (auto-masked from sums; y-write guarded).
    for (int l0 = 0; l0 < 36; l0 += 2) {
        const int l1 = l0 + 1;
        // ---- conv, pair-shared rows: rows l0..l0+9 read once, feed both outputs ----
        f32x4 cacc0 = {0.f,0.f,0.f,0.f};
        f32x4 cacc1 = {0.f,0.f,0.f,0.f};
        {
            const unsigned short* base = &s_seq[col * SEQ_STRIDE + l0 * CINP + quad * 8];
            short8 af = *(const short8*)base;                       // row l0 -> c0 tap 0
            cacc0 = __builtin_amdgcn_mfma_f32_16x16x32_bf16(wb2[0], af, cacc0, 0, 0, 0);
            #pragma unroll
            for (int d = 1; d <= 8; ++d) {                          // rows l0+1..l0+8
                af = *(const short8*)(base + d * CINP);
                cacc0 = __builtin_amdgcn_mfma_f32_16x16x32_bf16(wb2[d],     af, cacc0, 0, 0, 0);
                cacc1 = __builtin_amdgcn_mfma_f32_16x16x32_bf16(wb2[d - 1], af, cacc1, 0, 0, 0);
            }
            af = *(const short8*)(base + 9 * CINP);                 // row l0+9 -> c1 tap 8
            cacc1 = __builtin_amdgcn_mfma_f32_16x16x32_bf16(wb2[8], af, cacc1, 0, 0, 0);
        }
        // ---- epilogue: lane holds batch=col, f = 16*wave + 4q + r ----
        {
            float cm0 = (l0 >= 10 + plen_lane && l0 < 20 + plen_lane) ? 1.0f : 0.0f;
            float cm1 = (l1 >= 10 + plen_lane && l1 < 20 + plen_lane) ? 1.0f : 0.0f;
            float a0 = fmaxf(cacc0[0] + cbias[0], 0.0f);
            float a1 = fmaxf(cacc0[1] + cbias[1], 0.0f);
            float a2 = fmaxf(cacc0[2] + cbias[2], 0.0f);
            float a3 = fmaxf(cacc0[3] + cbias[3], 0.0f);
            float e0 = fmaxf(cacc1[0] + cbias[0], 0.0f);
            float e1 = fmaxf(cacc1[1] + cbias[1], 0.0f);
            float e2 = fmaxf(cacc1[2] + cbias[2], 0.0f);
            float e3 = fmaxf(cacc1[3] + cbias[3], 0.0f);
            if (l0 < 10) {            // wave-uniform
                sum_n[0] += a0; sum_n[1] += a1; sum_n[2] += a2; sum_n[3] += a3;
            }
            if (l1 < 10) {
                sum_n[0] += e0; sum_n[1] += e1; sum_n[2] += e2; sum_n[3] += e3;
            }
            sum_c[0] += cm0 * a0 + cm1 * e0;
            sum_c[1] += cm0 * a1 + cm1 * e1;
            sum_c[2] += cm0 * a2 + cm1 * e2;
            sum_c[3] += cm0 * a3 + cm1 * e3;
            ushort4 pk0 = { bf16bits(a0), bf16bits(a1), bf16bits(a2), bf16bits(a3) };
            ushort4 pk1 = { bf16bits(e0), bf16bits(e1), bf16bits(e2), bf16bits(e3) };
            *(ushort4*)&s_tile[l0 & 3][col * TILE_STRIDE + wave * 16 + 4 * quad] = pk0;
            *(ushort4*)&s_tile[l1 & 3][col * TILE_STRIDE + wave * 16 + 4 * quad] = pk1;
        }
        __syncthreads();   // conv tiles written -> MLP may read; WAR fence for ring

        // ---- MLP layer1 GEMM: D[m=batch][n = wave's 16-n tile], K = 128 f ----
        short8 am0[4], am1[4];
        #pragma unroll
        for (int s = 0; s < 4; s++) {
            am0[s] = *(const short8*)&s_tile[l0 & 3][col * TILE_STRIDE + 32 * s + quad * 8];
            am1[s] = *(const short8*)&s_tile[l1 & 3][col * TILE_STRIDE + 32 * s + quad * 8];
        }
        f32x4 hacc0 = {0.f,0.f,0.f,0.f};
        f32x4 hacc1 = {0.f,0.f,0.f,0.f};
        #pragma unroll
        for (int s = 0; s < 4; s++) {
            hacc0 = __builtin_amdgcn_mfma_f32_16x16x32_bf16(am0[s], w1b[s], hacc0, 0, 0, 0);
            hacc1 = __builtin_amdgcn_mfma_f32_16x16x32_bf16(am1[s], w1b[s], hacc1, 0, 0, 0);
        }
        // ---- y partial = relu(h+b1) @ w2 over this wave's 16 n; DPP row-sum ----
        float p0[4], p1[4];
        #pragma unroll
        for (int r = 0; r < 4; r++) {
            p0[r] = row_sum16(fmaxf(hacc0[r] + b1v, 0.f) * w2v);
            p1[r] = row_sum16(fmaxf(hacc1[r] + b1v, 0.f) * w2v);
        }
        if (col == 0) {                      // batch index = 4*quad + r
            *(f32x4*)&s_yp[l0 * YP_STRIDE + wave * 16 + quad * 4] =
                (f32x4){p0[0], p0[1], p0[2], p0[3]};
            if (l1 < Ln)
                *(f32x4*)&s_yp[l1 * YP_STRIDE + wave * 16 + quad * 4] =
                    (f32x4){p1[0], p1[1], p1[2], p1[3]};
        }
    }
    __syncthreads();   // all s_seq reads done -> overlay safe; s_yp complete

    // ---- flank-average partials: apply navg_w/cavg_w post-loop ----
    {
        float an = 0.f, ac = 0.f;
        #pragma unroll
        for (int r = 0; r < 4; r++) {
            int fidx = wave * 16 + 4 * quad + r;
            an += sum_n[r] * navg_w[fidx];
            ac += sum_c[r] * cavg_w[fidx];
        }
        an += __shfl_xor(an, 16); an += __shfl_xor(an, 32);   // sum over quads
        ac += __shfl_xor(ac, 16); ac += __shfl_xor(ac, 32);
        if (quad == 0) {                     // lane < 16: one per batch
            s_avg[wave * 2 * GB + 0 * GB + col] = an;
            s_avg[wave * 2 * GB + 1 * GB + col] = ac;
        }
    }
    __syncthreads();

    // ---- y finalize: y = tanh(sum of 4 wave-partials + b2), 1120 values ----
    // m-fastest decomposition: 64 lanes cover all 32 banks 2-way (conflict-free);
    // YP_STRIDE=136 decorrelates the per-l bank offset (136%32 = 8).
    {
        const float bn = n_b2[0], bc = c_b2[0];
        for (int i = t; i < 2 * GB * Ln; i += 512) {
            int m = i & 15, rem = i >> 4;        // rem = 0..69
            int l = rem % Ln, hd = rem / Ln;
            float v = (hd ? bc : bn);
            #pragma unroll
            for (int w = 0; w < 4; w++)
                v += s_yp[l * YP_STRIDE + (hd * 4 + w) * 16 + m];
            s_y[hd * GB * 36 + m * 36 + l] = tanhf(v);
        }
    }
    __syncthreads();

    // ---- final combine: one thread per batch row ----
    if (t < GB) {
        const int m = t;
        const int plen = plen_arr[b0 + m];
        const float* ym = s_y + m * 36;               // n-head row
        const float* yc = s_y + GB * 36 + m * 36;     // c-head row
        float cleaved_n = ym[10];
        float mn = 0.f;   // reference maxes (y+1)*mask over ALL l; unmasked give 0
        for (int l = 11; l < 10 + plen; l++) mn = fmaxf(mn, ym[l] + 1.f);
        float maxpool_n = -(mn - 1.f);
        float cleaved_c = yc[10 + plen - 1];
        float mc = 0.f;
        for (int l = 10; l < 10 + plen - 1; l++) mc = fmaxf(mc, yc[l] + 1.f);
        float maxpool_c = -(mc - 1.f);
        float sn = 0.f, sc = 0.f;
        #pragma unroll
        for (int w = 0; w < 8; w++) {
            sn += s_avg[w * 2 * GB + 0 * GB + m];
            sc += s_avg[w * 2 * GB + 1 * GB + m];
        }
        float avg_n = tanhf(sn * 0.1f + navg_b[0]);
        float avg_c = tanhf(sc * 0.1f + cavg_b[0]);
        float comb = cleaved_n * out_w[0] + maxpool_n * out_w[1] + avg_n * out_w[2]
                   + cleaved_c * out_w[3] + maxpool_c * out_w[4] + avg_c * out_w[5]
                   + out_b[0];
        out[b0 + m] = 1.f / (1.f + expf(-comb));
    }
}

extern "C" void kernel_launch(void* const* d_in, const int* in_sizes, int n_in,
                              void* d_out, int out_size, void* d_ws, size_t ws_size,
                              hipStream_t stream) {
    const int B = in_sizes[1];
    fused_kernel<<<B / GB, 512, 0, stream>>>(
        (const float*)d_in[0],  (const int*)d_in[1],
        (const float*)d_in[2],  (const float*)d_in[3],
        (const float*)d_in[4],  (const float*)d_in[5],
        (const float*)d_in[6],  (const float*)d_in[7],
        (const float*)d_in[8],  (const float*)d_in[9],
        (const float*)d_in[10], (const float*)d_in[11],
        (const float*)d_in[12], (const float*)d_in[13],
        (const float*)d_in[14], (const float*)d_in[15],
        (const float*)d_in[16], (const float*)d_in[17],
        (float*)d_out);
}

// Round 7
// 383.404 us; speedup vs baseline: 1.0933x; 1.0933x over previous
//
#include <hip/hip_runtime.h>
#include <hip/hip_bf16.h>
#include <math.h>

// Problem constants
#define Ln     35
#define CINn   21
#define CINP   24        // padded CIN (shorts per padded row; 48B rows -> 16B-aligned reads)
#define Fn     128
#define Kn     9
#define Hn     64
#define GB     16        // batch rows per block
#define SEQ_STRIDE 1064  // 44 rows*24 + 8 slack (shorts); row 43+32-short read ends exactly at 1064
#define TILE_STRIDE 136  // 128 + 8 pad (shorts)
#define YP_STRIDE 136    // floats per l in s_yp: 8 waves*16 batch + 8 pad (bank decorrelate)

typedef __attribute__((ext_vector_type(8))) short short8;
typedef __attribute__((ext_vector_type(4))) float f32x4;

static __device__ __forceinline__ unsigned short bf16bits(float f) {
    __hip_bfloat16 h = __float2bfloat16(f);
    return *(unsigned short*)&h;
}

// f32 lane-row (16-lane) sum via DPP rotate-accumulate: VALU pipe, zero LDS traffic.
// row_ror:N dpp_ctrl = 0x120|N. After ror 8,4,2,1 every lane holds the row total.
// (numerically validated rounds 4-6; replaces 4x ds_swizzle per value)
template <int CTRL>
static __device__ __forceinline__ float dpp_add(float v) {
    int r = __builtin_amdgcn_update_dpp(0, __builtin_bit_cast(int, v),
                                        CTRL, 0xF, 0xF, true);
    return v + __builtin_bit_cast(float, r);
}
static __device__ __forceinline__ float row_sum16(float v) {
    v = dpp_add<0x128>(v);   // ror 8
    v = dpp_add<0x124>(v);   // ror 4
    v = dpp_add<0x122>(v);   // ror 2
    v = dpp_add<0x121>(v);   // ror 1
    return v;
}

// ---------------- single fused kernel: 16 batch rows / block, 512 threads ----------------
// 8 waves/block; wave w owns conv f-tile [16w,16w+16) and MLP n-tile [16w,16w+16)
// (n<64 = n-head, n>=64 = c-head).
// STRUCTURE RULES (hard-won, rounds 1-6):
//  * Uniform 18-stage loop, straight-line bodies, explicit up-front fragment ARRAYS
//    then pure MFMA chains. This is the only allocator-friendly shape found:
//    region-peeling (r1-3), 4-wave/2-tile (r4), and serial reused-af interleave (r6)
//    ALL spilled to scratch (WRITE_SIZE 90-336 MB vs 0.13 MB clean).
//  * Gate every structural edit on WRITE_SIZE == 128 KiB.
// Round-7 delta (pair-shared conv, round-5 shape): conv per stage reads padded rows
// l0..l0+9 ONCE each into af[10] (10 b128 vs round-5's 14), then two 9-tap K=32 MFMA
// chains: cacc0 += W[d]*row(l0+d), cacc1 += W[d]*row(l1+d) = wb2[d]*af[d+1].
// Row reads are 32 shorts; kk>=21 lanes multiply zero-padded taps (wb2[k][c>=21]=0),
// so the overhang into the next row is auto-masked (verified numerically in round 6).
__global__ __launch_bounds__(512, 4) void fused_kernel(
    const float* __restrict__ seq,    const int*   __restrict__ plen_arr,
    const float* __restrict__ conv_w, const float* __restrict__ conv_b,
    const float* __restrict__ n_w1,   const float* __restrict__ n_b1,
    const float* __restrict__ n_w2,   const float* __restrict__ n_b2,
    const float* __restrict__ c_w1,   const float* __restrict__ c_b1,
    const float* __restrict__ c_w2,   const float* __restrict__ c_b2,
    const float* __restrict__ navg_w, const float* __restrict__ navg_b,
    const float* __restrict__ cavg_w, const float* __restrict__ cavg_b,
    const float* __restrict__ out_w,  const float* __restrict__ out_b,
    float* __restrict__ out)
{
    __shared__ __align__(16) unsigned short s_seq[GB * SEQ_STRIDE];      // 34048 B
    __shared__ __align__(16) unsigned short s_tile[4][GB * TILE_STRIDE]; // 17408 B
    __shared__ __align__(16) float s_yp[Ln * YP_STRIDE];                 // 19040 B: [l][wave*16+m]
    // overlays on s_seq (dead after the main loop):
    float* s_y   = (float*)s_seq;            // [2][GB][36] = 1152 floats
    float* s_avg = (float*)s_seq + 1152;     // [8 waves][2][GB] = 256 floats

    const int t    = threadIdx.x;
    const int wave = t >> 6;                 // 0..7
    const int lane = t & 63;
    const int quad = lane >> 4;
    const int col  = lane & 15;
    const int b0   = blockIdx.x * GB;

    // ---- zero-init padded seq (pad rows/channels + slack must be 0) ----
    {
        uint4* p = (uint4*)s_seq;            // 34048/16 = 2128 uint4
        for (int i = t; i < (GB * SEQ_STRIDE) / 8; i += 512)
            p[i] = make_uint4(0u, 0u, 0u, 0u);
    }

    // ---- per-lane loop-invariant weight fragments (single tile per wave) ----
    // conv A-frag per tap k (operand-swapped): A[m=f=16*wave+col][c=quad*8+j], c>=21 -> 0
    // MLP  B-frag: B[k=f][n=16*wave+col]
    short8 wb2[9];
    short8 w1b[4];
    float  cbias[4], b1v, w2v;
    const int head = wave >> 2;              // 0 = n-head (waves 0-3), 1 = c (waves 4-7)
    {
        const int ng = wave * 16 + col;      // conv f (A m-index) AND mlp n-index
        #pragma unroll
        for (int k = 0; k < 9; k++) {
            short8 v;
            #pragma unroll
            for (int j = 0; j < 8; j++) {
                int c = quad * 8 + j;
                float f = (c < CINn) ? conv_w[(k * CINn + c) * Fn + ng] : 0.0f;
                v[j] = (short)bf16bits(f);
            }
            wb2[k] = v;
        }
        const int nl = ng & 63;
        #pragma unroll
        for (int s = 0; s < 4; s++) {
            short8 v;
            #pragma unroll
            for (int j = 0; j < 8; j++) {
                int k = 32 * s + quad * 8 + j;
                float f = head ? c_w1[k * Hn + nl] : n_w1[k * Hn + nl];
                v[j] = (short)bf16bits(f);
            }
            w1b[s] = v;
        }
        #pragma unroll
        for (int r = 0; r < 4; r++)
            cbias[r] = conv_b[wave * 16 + 4 * quad + r];
        b1v = head ? c_b1[nl] : n_b1[nl];
        w2v = head ? c_w2[nl] : n_w2[nl];
    }
    const int plen_lane = plen_arr[b0 + col];   // this lane's batch (=col) plen

    __syncthreads();   // zero-init done before data fill

    // ---- stage seq -> bf16 LDS, rows shifted +4 (SAME pad), c<21 only ----
    for (int i = t; i < GB * Ln * CINn; i += 512) {
        int bi = i / (Ln * CINn), r = i % (Ln * CINn);
        int l = r / CINn, c = r % CINn;
        s_seq[bi * SEQ_STRIDE + (4 + l) * CINP + c] =
            bf16bits(seq[(size_t)(b0 + bi) * (Ln * CINn) + r]);
    }
    __syncthreads();

    float sum_n[4] = {0.f,0.f,0.f,0.f};
    float sum_c[4] = {0.f,0.f,0.f,0.f};

    // ---- main loop: 2 l per stage, 18 stages, 1 barrier each. 4-slot ring:
    // stage i writes slots {2i&3,(2i+1)&3}; WAR on a slot is fenced 1 stage later.
    // l=35 is a computed pad column (auto-masked from sums; y-write guarded).
    for (int l0 = 0; l0 < 36; l0 += 2) {
        const int l1 = l0 + 1;
        // ---- conv, pair-shared rows: af[10] read once (explicit array, round-5 shape),
        //      then two independent 9-MFMA K=32 chains ----
        f32x4 cacc0 = {0.f,0.f,0.f,0.f};
        f32x4 cacc1 = {0.f,0.f,0.f,0.f};
        {
            short8 af[10];
            #pragma unroll
            for (int d = 0; d < 10; ++d)
                af[d] = *(const short8*)&s_seq[col * SEQ_STRIDE + (l0 + d) * CINP + quad * 8];
            #pragma unroll
            for (int d = 0; d < 9; ++d)
                cacc0 = __builtin_amdgcn_mfma_f32_16x16x32_bf16(wb2[d], af[d], cacc0, 0, 0, 0);
            #pragma unroll
            for (int d = 0; d < 9; ++d)
                cacc1 = __builtin_amdgcn_mfma_f32_16x16x32_bf16(wb2[d], af[d + 1], cacc1, 0, 0, 0);
        }
        // ---- epilogue: lane holds batch=col, f = 16*wave + 4q + r ----
        {
            float cm0 = (l0 >= 10 + plen_lane && l0 < 20 + plen_lane) ? 1.0f : 0.0f;
            float cm1 = (l1 >= 10 + plen_lane && l1 < 20 + plen_lane) ? 1.0f : 0.0f;
            float a0 = fmaxf(cacc0[0] + cbias[0], 0.0f);
            float a1 = fmaxf(cacc0[1] + cbias[1], 0.0f);
            float a2 = fmaxf(cacc0[2] + cbias[2], 0.0f);
            float a3 = fmaxf(cacc0[3] + cbias[3], 0.0f);
            float e0 = fmaxf(cacc1[0] + cbias[0], 0.0f);
            float e1 = fmaxf(cacc1[1] + cbias[1], 0.0f);
            float e2 = fmaxf(cacc1[2] + cbias[2], 0.0f);
            float e3 = fmaxf(cacc1[3] + cbias[3], 0.0f);
            if (l0 < 10) {            // wave-uniform
                sum_n[0] += a0; sum_n[1] += a1; sum_n[2] += a2; sum_n[3] += a3;
            }
            if (l1 < 10) {
                sum_n[0] += e0; sum_n[1] += e1; sum_n[2] += e2; sum_n[3] += e3;
            }
            sum_c[0] += cm0 * a0 + cm1 * e0;
            sum_c[1] += cm0 * a1 + cm1 * e1;
            sum_c[2] += cm0 * a2 + cm1 * e2;
            sum_c[3] += cm0 * a3 + cm1 * e3;
            ushort4 pk0 = { bf16bits(a0), bf16bits(a1), bf16bits(a2), bf16bits(a3) };
            ushort4 pk1 = { bf16bits(e0), bf16bits(e1), bf16bits(e2), bf16bits(e3) };
            *(ushort4*)&s_tile[l0 & 3][col * TILE_STRIDE + wave * 16 + 4 * quad] = pk0;
            *(ushort4*)&s_tile[l1 & 3][col * TILE_STRIDE + wave * 16 + 4 * quad] = pk1;
        }
        __syncthreads();   // conv tiles written -> MLP may read; WAR fence for ring

        // ---- MLP layer1 GEMM: D[m=batch][n = wave's 16-n tile], K = 128 f ----
        short8 am0[4], am1[4];
        #pragma unroll
        for (int s = 0; s < 4; s++) {
            am0[s] = *(const short8*)&s_tile[l0 & 3][col * TILE_STRIDE + 32 * s + quad * 8];
            am1[s] = *(const short8*)&s_tile[l1 & 3][col * TILE_STRIDE + 32 * s + quad * 8];
        }
        f32x4 hacc0 = {0.f,0.f,0.f,0.f};
        f32x4 hacc1 = {0.f,0.f,0.f,0.f};
        #pragma unroll
        for (int s = 0; s < 4; s++) {
            hacc0 = __builtin_amdgcn_mfma_f32_16x16x32_bf16(am0[s], w1b[s], hacc0, 0, 0, 0);
            hacc1 = __builtin_amdgcn_mfma_f32_16x16x32_bf16(am1[s], w1b[s], hacc1, 0, 0, 0);
        }
        // ---- y partial = relu(h+b1) @ w2 over this wave's 16 n; DPP row-sum ----
        float p0[4], p1[4];
        #pragma unroll
        for (int r = 0; r < 4; r++) {
            p0[r] = row_sum16(fmaxf(hacc0[r] + b1v, 0.f) * w2v);
            p1[r] = row_sum16(fmaxf(hacc1[r] + b1v, 0.f) * w2v);
        }
        if (col == 0) {                      // batch index = 4*quad + r
            *(f32x4*)&s_yp[l0 * YP_STRIDE + wave * 16 + quad * 4] =
                (f32x4){p0[0], p0[1], p0[2], p0[3]};
            if (l1 < Ln)
                *(f32x4*)&s_yp[l1 * YP_STRIDE + wave * 16 + quad * 4] =
                    (f32x4){p1[0], p1[1], p1[2], p1[3]};
        }
    }
    __syncthreads();   // all s_seq reads done -> overlay safe; s_yp complete

    // ---- flank-average partials: apply navg_w/cavg_w post-loop ----
    {
        float an = 0.f, ac = 0.f;
        #pragma unroll
        for (int r = 0; r < 4; r++) {
            int fidx = wave * 16 + 4 * quad + r;
            an += sum_n[r] * navg_w[fidx];
            ac += sum_c[r] * cavg_w[fidx];
        }
        an += __shfl_xor(an, 16); an += __shfl_xor(an, 32);   // sum over quads
        ac += __shfl_xor(ac, 16); ac += __shfl_xor(ac, 32);
        if (quad == 0) {                     // lane < 16: one per batch
            s_avg[wave * 2 * GB + 0 * GB + col] = an;
            s_avg[wave * 2 * GB + 1 * GB + col] = ac;
        }
    }
    __syncthreads();

    // ---- y finalize: y = tanh(sum of 4 wave-partials + b2), 1120 values ----
    // m-fastest decomposition: 64 lanes cover all 32 banks 2-way (conflict-free);
    // YP_STRIDE=136 decorrelates the per-l bank offset (136%32 = 8).
    {
        const float bn = n_b2[0], bc = c_b2[0];
        for (int i = t; i < 2 * GB * Ln; i += 512) {
            int m = i & 15, rem = i >> 4;        // rem = 0..69
            int l = rem % Ln, hd = rem / Ln;
            float v = (hd ? bc : bn);
            #pragma unroll
            for (int w = 0; w < 4; w++)
                v += s_yp[l * YP_STRIDE + (hd * 4 + w) * 16 + m];
            s_y[hd * GB * 36 + m * 36 + l] = tanhf(v);
        }
    }
    __syncthreads();

    // ---- final combine: one thread per batch row ----
    if (t < GB) {
        const int m = t;
        const int plen = plen_arr[b0 + m];
        const float* ym = s_y + m * 36;               // n-head row
        const float* yc = s_y + GB * 36 + m * 36;     // c-head row
        float cleaved_n = ym[10];
        float mn = 0.f;   // reference maxes (y+1)*mask over ALL l; unmasked give 0
        for (int l = 11; l < 10 + plen; l++) mn = fmaxf(mn, ym[l] + 1.f);
        float maxpool_n = -(mn - 1.f);
        float cleaved_c = yc[10 + plen - 1];
        float mc = 0.f;
        for (int l = 10; l < 10 + plen - 1; l++) mc = fmaxf(mc, yc[l] + 1.f);
        float maxpool_c = -(mc - 1.f);
        float sn = 0.f, sc = 0.f;
        #pragma unroll
        for (int w = 0; w < 8; w++) {
            sn += s_avg[w * 2 * GB + 0 * GB + m];
            sc += s_avg[w * 2 * GB + 1 * GB + m];
        }
        float avg_n = tanhf(sn * 0.1f + navg_b[0]);
        float avg_c = tanhf(sc * 0.1f + cavg_b[0]);
        float comb = cleaved_n * out_w[0] + maxpool_n * out_w[1] + avg_n * out_w[2]
                   + cleaved_c * out_w[3] + maxpool_c * out_w[4] + avg_c * out_w[5]
                   + out_b[0];
        out[b0 + m] = 1.f / (1.f + expf(-comb));
    }
}

extern "C" void kernel_launch(void* const* d_in, const int* in_sizes, int n_in,
                              void* d_out, int out_size, void* d_ws, size_t ws_size,
                              hipStream_t stream) {
    const int B = in_sizes[1];
    fused_kernel<<<B / GB, 512, 0, stream>>>(
        (const float*)d_in[0],  (const int*)d_in[1],
        (const float*)d_in[2],  (const float*)d_in[3],
        (const float*)d_in[4],  (const float*)d_in[5],
        (const float*)d_in[6],  (const float*)d_in[7],
        (const float*)d_in[8],  (const float*)d_in[9],
        (const float*)d_in[10], (const float*)d_in[11],
        (const float*)d_in[12], (const float*)d_in[13],
        (const float*)d_in[14], (const float*)d_in[15],
        (const float*)d_in[16], (const float*)d_in[17],
        (float*)d_out);
}

// Round 8
// 321.089 us; speedup vs baseline: 1.3055x; 1.1941x over previous
//
#include <hip/hip_runtime.h>
#include <hip/hip_bf16.h>
#include <math.h>

// Problem constants
#define Ln     35
#define CINn   21
#define CINP   24        // padded CIN (multiple of 8 -> aligned b128 im2col reads)
#define Fn     128
#define Kn     9
#define Hn     64
#define GB     16        // batch rows per block
#define SEQ_STRIDE 1064  // 44 rows*24 + 8 slack (shorts); l=35 window ends at 1064
#define TILE_STRIDE 136  // 128 + 8 pad (shorts)
#define YP_STRIDE 136    // floats per l in s_yp: 8 waves*16 batch + 8 pad (bank decorrelate)

typedef __attribute__((ext_vector_type(8))) short short8;
typedef __attribute__((ext_vector_type(4))) float f32x4;

static __device__ __forceinline__ unsigned short bf16bits(float f) {
    __hip_bfloat16 h = __float2bfloat16(f);
    return *(unsigned short*)&h;
}

// f32 lane-row (16-lane) sum via DPP rotate-accumulate: VALU pipe, zero LDS traffic.
// row_ror:N dpp_ctrl = 0x120|N. After ror 8,4,2,1 every lane holds the row total.
// (numerically validated rounds 4-7; replaces 4x ds_swizzle per value)
template <int CTRL>
static __device__ __forceinline__ float dpp_add(float v) {
    int r = __builtin_amdgcn_update_dpp(0, __builtin_bit_cast(int, v),
                                        CTRL, 0xF, 0xF, true);
    return v + __builtin_bit_cast(float, r);
}
static __device__ __forceinline__ float row_sum16(float v) {
    v = dpp_add<0x128>(v);   // ror 8
    v = dpp_add<0x124>(v);   // ror 4
    v = dpp_add<0x122>(v);   // ror 2
    v = dpp_add<0x121>(v);   // ror 1
    return v;
}

// ---------------- single fused kernel: 16 batch rows / block, 512 threads ----------------
// 8 waves/block; wave w owns conv f-tile [16w,16w+16) and MLP n-tile [16w,16w+16)
// (n<64 = n-head, n>=64 = c-head). Weight frags per wave: 28+16 = 44 VGPRs.
// STRUCTURE RULES (hard-won, rounds 1-7):
//  * This uniform 18-stage loop with explicit af0[7]/af1[7] fragment arrays is the
//    ONLY verified spill-free shape (WRITE_SIZE == output, 128 KiB). Region-peeling
//    (r1-3), 4-wave/2-tile (r4), and pair-shared conv reads (r6,r7) ALL spilled.
//  * Gate every structural edit on WRITE_SIZE == 128 KiB.
//  * Conv b128 bank pattern is already at the wave64 floor (8 addrs/bank); the
//    SQ_LDS_BANK_CONFLICT count is intrinsic b128 cost, ~4.4 cyc/read. Don't swizzle.
// Round-8 delta: MLP section (tile write + barrier + MLP GEMM + rowsum + s_yp write)
// runs ONLY for l0 in [10,26) -- the only l whose y is consumed (l in [10,24];
// plen<=15). Single block-uniform `if`, no values defined inside escape it.
// 8 of 18 stages keep barriers; conv/sums run every stage as before.
__global__ __launch_bounds__(512, 4) void fused_kernel(
    const float* __restrict__ seq,    const int*   __restrict__ plen_arr,
    const float* __restrict__ conv_w, const float* __restrict__ conv_b,
    const float* __restrict__ n_w1,   const float* __restrict__ n_b1,
    const float* __restrict__ n_w2,   const float* __restrict__ n_b2,
    const float* __restrict__ c_w1,   const float* __restrict__ c_b1,
    const float* __restrict__ c_w2,   const float* __restrict__ c_b2,
    const float* __restrict__ navg_w, const float* __restrict__ navg_b,
    const float* __restrict__ cavg_w, const float* __restrict__ cavg_b,
    const float* __restrict__ out_w,  const float* __restrict__ out_b,
    float* __restrict__ out)
{
    __shared__ __align__(16) unsigned short s_seq[GB * SEQ_STRIDE];      // 34048 B
    __shared__ __align__(16) unsigned short s_tile[4][GB * TILE_STRIDE]; // 17408 B
    __shared__ __align__(16) float s_yp[Ln * YP_STRIDE];                 // 19040 B: [l][wave*16+m]
    // overlays on s_seq (dead after the main loop):
    float* s_y   = (float*)s_seq;            // [2][GB][36] = 1152 floats
    float* s_avg = (float*)s_seq + 1152;     // [8 waves][2][GB] = 256 floats

    const int t    = threadIdx.x;
    const int wave = t >> 6;                 // 0..7
    const int lane = t & 63;
    const int quad = lane >> 4;
    const int col  = lane & 15;
    const int b0   = blockIdx.x * GB;

    // ---- zero-init padded seq (pad rows/channels + slack must be 0) ----
    {
        uint4* p = (uint4*)s_seq;            // 34048/16 = 2128 uint4
        for (int i = t; i < (GB * SEQ_STRIDE) / 8; i += 512)
            p[i] = make_uint4(0u, 0u, 0u, 0u);
    }

    // ---- per-lane loop-invariant weight fragments (single tile per wave) ----
    // conv A-frag (operand-swapped): A[m=f=16*wave+col][k=kk], kk = k*24+c
    // MLP  B-frag: B[k=f][n=16*wave+col]
    short8 wb[7];
    short8 w1b[4];
    float  cbias[4], b1v, w2v;
    const int head = wave >> 2;              // 0 = n-head (waves 0-3), 1 = c (waves 4-7)
    {
        const int ng = wave * 16 + col;      // conv f (A m-index) AND mlp n-index
        #pragma unroll
        for (int s = 0; s < 7; s++) {
            short8 v;
            #pragma unroll
            for (int j = 0; j < 8; j++) {
                int kk = 32 * s + quad * 8 + j;
                int k = kk / CINP, c = kk % CINP;
                float f = (k < Kn && c < CINn) ? conv_w[(k * CINn + c) * Fn + ng] : 0.0f;
                v[j] = (short)bf16bits(f);
            }
            wb[s] = v;
        }
        const int nl = ng & 63;
        #pragma unroll
        for (int s = 0; s < 4; s++) {
            short8 v;
            #pragma unroll
            for (int j = 0; j < 8; j++) {
                int k = 32 * s + quad * 8 + j;
                float f = head ? c_w1[k * Hn + nl] : n_w1[k * Hn + nl];
                v[j] = (short)bf16bits(f);
            }
            w1b[s] = v;
        }
        #pragma unroll
        for (int r = 0; r < 4; r++)
            cbias[r] = conv_b[wave * 16 + 4 * quad + r];
        b1v = head ? c_b1[nl] : n_b1[nl];
        w2v = head ? c_w2[nl] : n_w2[nl];
    }
    const int plen_lane = plen_arr[b0 + col];   // this lane's batch (=col) plen

    __syncthreads();   // zero-init done before data fill

    // ---- stage seq -> bf16 LDS, rows shifted +4 (SAME pad), c<21 only ----
    for (int i = t; i < GB * Ln * CINn; i += 512) {
        int bi = i / (Ln * CINn), r = i % (Ln * CINn);
        int l = r / CINn, c = r % CINn;
        s_seq[bi * SEQ_STRIDE + (4 + l) * CINP + c] =
            bf16bits(seq[(size_t)(b0 + bi) * (Ln * CINn) + r]);
    }
    __syncthreads();

    float sum_n[4] = {0.f,0.f,0.f,0.f};
    float sum_c[4] = {0.f,0.f,0.f,0.f};

    // ---- main loop: 2 l per stage, 18 stages. Barrier + MLP only in the 8 stages
    // with l0 in [10,26). 4-slot ring on s_tile: slots only written/reused within
    // barrier-bearing stages -> WAR still fenced. l=35 = computed pad (auto-masked).
    for (int l0 = 0; l0 < 36; l0 += 2) {
        const int l1 = l0 + 1;
        // ---- conv GEMM (operand-swapped): D^T[f][batch], wave's 16-f tile ----
        short8 af0[7], af1[7];
        #pragma unroll
        for (int s = 0; s < 7; s++) {
            af0[s] = *(const short8*)&s_seq[col * SEQ_STRIDE + l0 * CINP + 32 * s + quad * 8];
            af1[s] = *(const short8*)&s_seq[col * SEQ_STRIDE + l1 * CINP + 32 * s + quad * 8];
        }
        f32x4 cacc0 = {0.f,0.f,0.f,0.f};
        f32x4 cacc1 = {0.f,0.f,0.f,0.f};
        #pragma unroll
        for (int s = 0; s < 7; s++) {
            cacc0 = __builtin_amdgcn_mfma_f32_16x16x32_bf16(wb[s], af0[s], cacc0, 0, 0, 0);
            cacc1 = __builtin_amdgcn_mfma_f32_16x16x32_bf16(wb[s], af1[s], cacc1, 0, 0, 0);
        }
        // ---- epilogue: lane holds batch=col, f = 16*wave + 4q + r ----
        float a0 = fmaxf(cacc0[0] + cbias[0], 0.0f);
        float a1 = fmaxf(cacc0[1] + cbias[1], 0.0f);
        float a2 = fmaxf(cacc0[2] + cbias[2], 0.0f);
        float a3 = fmaxf(cacc0[3] + cbias[3], 0.0f);
        float e0 = fmaxf(cacc1[0] + cbias[0], 0.0f);
        float e1 = fmaxf(cacc1[1] + cbias[1], 0.0f);
        float e2 = fmaxf(cacc1[2] + cbias[2], 0.0f);
        float e3 = fmaxf(cacc1[3] + cbias[3], 0.0f);
        {
            float cm0 = (l0 >= 10 + plen_lane && l0 < 20 + plen_lane) ? 1.0f : 0.0f;
            float cm1 = (l1 >= 10 + plen_lane && l1 < 20 + plen_lane) ? 1.0f : 0.0f;
            if (l0 < 10) {            // wave-uniform
                sum_n[0] += a0; sum_n[1] += a1; sum_n[2] += a2; sum_n[3] += a3;
            }
            if (l1 < 10) {
                sum_n[0] += e0; sum_n[1] += e1; sum_n[2] += e2; sum_n[3] += e3;
            }
            sum_c[0] += cm0 * a0 + cm1 * e0;
            sum_c[1] += cm0 * a1 + cm1 * e1;
            sum_c[2] += cm0 * a2 + cm1 * e2;
            sum_c[3] += cm0 * a3 + cm1 * e3;
        }

        // ---- MLP section: only for l whose y is consumed (l in [10,25]) ----
        if (l0 >= 10 && l0 < 26) {           // block-uniform; barrier inside is legal
            ushort4 pk0 = { bf16bits(a0), bf16bits(a1), bf16bits(a2), bf16bits(a3) };
            ushort4 pk1 = { bf16bits(e0), bf16bits(e1), bf16bits(e2), bf16bits(e3) };
            *(ushort4*)&s_tile[l0 & 3][col * TILE_STRIDE + wave * 16 + 4 * quad] = pk0;
            *(ushort4*)&s_tile[l1 & 3][col * TILE_STRIDE + wave * 16 + 4 * quad] = pk1;
            __syncthreads();   // conv tiles written -> MLP may read; WAR fence for ring

            // ---- MLP layer1 GEMM: D[m=batch][n = wave's 16-n tile], K = 128 f ----
            short8 am0[4], am1[4];
            #pragma unroll
            for (int s = 0; s < 4; s++) {
                am0[s] = *(const short8*)&s_tile[l0 & 3][col * TILE_STRIDE + 32 * s + quad * 8];
                am1[s] = *(const short8*)&s_tile[l1 & 3][col * TILE_STRIDE + 32 * s + quad * 8];
            }
            f32x4 hacc0 = {0.f,0.f,0.f,0.f};
            f32x4 hacc1 = {0.f,0.f,0.f,0.f};
            #pragma unroll
            for (int s = 0; s < 4; s++) {
                hacc0 = __builtin_amdgcn_mfma_f32_16x16x32_bf16(am0[s], w1b[s], hacc0, 0, 0, 0);
                hacc1 = __builtin_amdgcn_mfma_f32_16x16x32_bf16(am1[s], w1b[s], hacc1, 0, 0, 0);
            }
            // ---- y partial = relu(h+b1) @ w2 over this wave's 16 n; DPP row-sum ----
            float p0[4], p1[4];
            #pragma unroll
            for (int r = 0; r < 4; r++) {
                p0[r] = row_sum16(fmaxf(hacc0[r] + b1v, 0.f) * w2v);
                p1[r] = row_sum16(fmaxf(hacc1[r] + b1v, 0.f) * w2v);
            }
            if (col == 0) {                  // batch index = 4*quad + r; l1 <= 25 < Ln
                *(f32x4*)&s_yp[l0 * YP_STRIDE + wave * 16 + quad * 4] =
                    (f32x4){p0[0], p0[1], p0[2], p0[3]};
                *(f32x4*)&s_yp[l1 * YP_STRIDE + wave * 16 + quad * 4] =
                    (f32x4){p1[0], p1[1], p1[2], p1[3]};
            }
        }
    }
    __syncthreads();   // all s_seq reads done -> overlay safe; s_yp complete

    // ---- flank-average partials: apply navg_w/cavg_w post-loop ----
    {
        float an = 0.f, ac = 0.f;
        #pragma unroll
        for (int r = 0; r < 4; r++) {
            int fidx = wave * 16 + 4 * quad + r;
            an += sum_n[r] * navg_w[fidx];
            ac += sum_c[r] * cavg_w[fidx];
        }
        an += __shfl_xor(an, 16); an += __shfl_xor(an, 32);   // sum over quads
        ac += __shfl_xor(ac, 16); ac += __shfl_xor(ac, 32);
        if (quad == 0) {                     // lane < 16: one per batch
            s_avg[wave * 2 * GB + 0 * GB + col] = an;
            s_avg[wave * 2 * GB + 1 * GB + col] = ac;
        }
    }
    __syncthreads();

    // ---- y finalize: y = tanh(sum of 4 wave-partials + b2), l in [10,25] only ----
    // (y outside [10,24] is never consumed; [10,25] written by the loop. 512 values.)
    // m-fastest decomposition: 64 lanes cover all 32 banks 2-way (conflict-free).
    {
        const float bn = n_b2[0], bc = c_b2[0];
        for (int i = t; i < 2 * GB * 16; i += 512) {
            int m = i & 15, rem = i >> 4;        // rem = 0..31
            int l = 10 + (rem & 15), hd = rem >> 4;
            float v = (hd ? bc : bn);
            #pragma unroll
            for (int w = 0; w < 4; w++)
                v += s_yp[l * YP_STRIDE + (hd * 4 + w) * 16 + m];
            s_y[hd * GB * 36 + m * 36 + l] = tanhf(v);
        }
    }
    __syncthreads();

    // ---- final combine: one thread per batch row ----
    if (t < GB) {
        const int m = t;
        const int plen = plen_arr[b0 + m];
        const float* ym = s_y + m * 36;               // n-head row
        const float* yc = s_y + GB * 36 + m * 36;     // c-head row
        float cleaved_n = ym[10];
        float mn = 0.f;   // reference maxes (y+1)*mask over ALL l; unmasked give 0
        for (int l = 11; l < 10 + plen; l++) mn = fmaxf(mn, ym[l] + 1.f);
        float maxpool_n = -(mn - 1.f);
        float cleaved_c = yc[10 + plen - 1];
        float mc = 0.f;
        for (int l = 10; l < 10 + plen - 1; l++) mc = fmaxf(mc, yc[l] + 1.f);
        float maxpool_c = -(mc - 1.f);
        float sn = 0.f, sc = 0.f;
        #pragma unroll
        for (int w = 0; w < 8; w++) {
            sn += s_avg[w * 2 * GB + 0 * GB + m];
            sc += s_avg[w * 2 * GB + 1 * GB + m];
        }
        float avg_n = tanhf(sn * 0.1f + navg_b[0]);
        float avg_c = tanhf(sc * 0.1f + cavg_b[0]);
        float comb = cleaved_n * out_w[0] + maxpool_n * out_w[1] + avg_n * out_w[2]
                   + cleaved_c * out_w[3] + maxpool_c * out_w[4] + avg_c * out_w[5]
                   + out_b[0];
        out[b0 + m] = 1.f / (1.f + expf(-comb));
    }
}

extern "C" void kernel_launch(void* const* d_in, const int* in_sizes, int n_in,
                              void* d_out, int out_size, void* d_ws, size_t ws_size,
                              hipStream_t stream) {
    const int B = in_sizes[1];
    fused_kernel<<<B / GB, 512, 0, stream>>>(
        (const float*)d_in[0],  (const int*)d_in[1],
        (const float*)d_in[2],  (const float*)d_in[3],
        (const float*)d_in[4],  (const float*)d_in[5],
        (const float*)d_in[6],  (const float*)d_in[7],
        (const float*)d_in[8],  (const float*)d_in[9],
        (const float*)d_in[10], (const float*)d_in[11],
        (const float*)d_in[12], (const float*)d_in[13],
        (const float*)d_in[14], (const float*)d_in[15],
        (const float*)d_in[16], (const float*)d_in[17],
        (float*)d_out);
}

// Round 10
// 308.814 us; speedup vs baseline: 1.3574x; 1.0397x over previous
//
#include <hip/hip_runtime.h>
#include <hip/hip_bf16.h>
#include <math.h>

// Problem constants
#define Ln     35
#define CINn   21
#define CINP   24        // padded CIN (multiple of 8 -> aligned b128 im2col reads)
#define Fn     128
#define Kn     9
#define Hn     64
#define GB     16        // batch rows per block
#define SEQ_STRIDE 1064  // 44 rows*24 + 8 slack (shorts); l=35 window ends exactly at 1064
#define TILE_STRIDE 136  // 128 + 8 pad (shorts)
#define YP_STRIDE 136    // floats per l-row in s_yp: 8 waves*16 batch + 8 pad
#define NYL    16        // s_yp rows: l in [10,25] only (round-8 cut)

typedef __attribute__((ext_vector_type(8))) short short8;
typedef __attribute__((ext_vector_type(4))) float f32x4;

static __device__ __forceinline__ unsigned short bf16bits(float f) {
    __hip_bfloat16 h = __float2bfloat16(f);
    return *(unsigned short*)&h;
}

// f32 lane-row (16-lane) sum via DPP rotate-accumulate: VALU pipe, zero LDS traffic.
// row_ror:N dpp_ctrl = 0x120|N. After ror 8,4,2,1 every lane holds the row total.
template <int CTRL>
static __device__ __forceinline__ float dpp_add(float v) {
    int r = __builtin_amdgcn_update_dpp(0, __builtin_bit_cast(int, v),
                                        CTRL, 0xF, 0xF, true);
    return v + __builtin_bit_cast(float, r);
}
static __device__ __forceinline__ float row_sum16(float v) {
    v = dpp_add<0x128>(v);   // ror 8
    v = dpp_add<0x124>(v);   // ror 4
    v = dpp_add<0x122>(v);   // ror 2
    v = dpp_add<0x121>(v);   // ror 1
    return v;
}

// ---------------- single fused kernel: 16 batch rows / block, 512 threads ----------------
// 8 waves/block; wave w owns conv f-tile [16w,16w+16) and MLP n-tile [16w,16w+16)
// (n<64 = n-head, n>=64 = c-head). Weight frags per wave: 28+16 = 44 VGPRs.
// STRUCTURE RULES (hard-won, rounds 1-8):
//  * Uniform 18-stage loop, explicit af0[7]/af1[7] fragment arrays, block-uniform
//    `if` guards with NO values escaping them. Everything else spilled (r1-4, r6, r7).
//  * Gate every structural edit on WRITE_SIZE == 128 KiB (output only).
//  * Conv b128 bank pattern is at the wave64 floor (8 addrs/bank); conflict counter
//    tracks intrinsic b128 multi-phase cost. Don't swizzle; only fewer reads help.
// Round-10 deltas (round 9 resubmit after infra failure, one safety revert):
//  * s_yp shrunk 35 -> 16 l-rows (only l in [10,25] live since round 8): -10.3 KB.
//  * s_tile ring 4 -> 2 slots + second barrier after MLP (write{0,1};bar;read;bar
//    cadence makes the 2-slot WAR safe): -8.7 KB.
//  * LDS 70.6 -> 51.5 KB -> 3 blocks/CU from the LDS limit ALONE. Keep
//    __launch_bounds__(512,4): the 2nd arg is an allocator minimum, not a cap;
//    (512,6) would squeeze the VGPR budget to ~85 for no extra residency.
//  * Staging vectorized: float4 global loads, branch-free wrap-corrected LDS addrs.
__global__ __launch_bounds__(512, 4) void fused_kernel(
    const float* __restrict__ seq,    const int*   __restrict__ plen_arr,
    const float* __restrict__ conv_w, const float* __restrict__ conv_b,
    const float* __restrict__ n_w1,   const float* __restrict__ n_b1,
    const float* __restrict__ n_w2,   const float* __restrict__ n_b2,
    const float* __restrict__ c_w1,   const float* __restrict__ c_b1,
    const float* __restrict__ c_w2,   const float* __restrict__ c_b2,
    const float* __restrict__ navg_w, const float* __restrict__ navg_b,
    const float* __restrict__ cavg_w, const float* __restrict__ cavg_b,
    const float* __restrict__ out_w,  const float* __restrict__ out_b,
    float* __restrict__ out)
{
    __shared__ __align__(16) unsigned short s_seq[GB * SEQ_STRIDE];      // 34048 B
    __shared__ __align__(16) unsigned short s_tile[2][GB * TILE_STRIDE]; //  8704 B
    __shared__ __align__(16) float s_yp[NYL * YP_STRIDE];                //  8704 B: [l-10][wave*16+m]
    // overlays on s_seq (dead after the main loop):
    float* s_y   = (float*)s_seq;            // [2][GB][36] = 1152 floats
    float* s_avg = (float*)s_seq + 1152;     // [8 waves][2][GB] = 256 floats

    const int t    = threadIdx.x;
    const int wave = t >> 6;                 // 0..7
    const int lane = t & 63;
    const int quad = lane >> 4;
    const int col  = lane & 15;
    const int b0   = blockIdx.x * GB;

    // ---- zero-init padded seq (pad rows/channels + slack must be 0) ----
    {
        uint4* p = (uint4*)s_seq;            // 34048/16 = 2128 uint4
        for (int i = t; i < (GB * SEQ_STRIDE) / 8; i += 512)
            p[i] = make_uint4(0u, 0u, 0u, 0u);
    }

    // ---- per-lane loop-invariant weight fragments (single tile per wave) ----
    // conv A-frag (operand-swapped): A[m=f=16*wave+col][k=kk], kk = k*24+c
    // MLP  B-frag: B[k=f][n=16*wave+col]
    short8 wb[7];
    short8 w1b[4];
    float  cbias[4], b1v, w2v;
    const int head = wave >> 2;              // 0 = n-head (waves 0-3), 1 = c (waves 4-7)
    {
        const int ng = wave * 16 + col;      // conv f (A m-index) AND mlp n-index
        #pragma unroll
        for (int s = 0; s < 7; s++) {
            short8 v;
            #pragma unroll
            for (int j = 0; j < 8; j++) {
                int kk = 32 * s + quad * 8 + j;
                int k = kk / CINP, c = kk % CINP;
                float f = (k < Kn && c < CINn) ? conv_w[(k * CINn + c) * Fn + ng] : 0.0f;
                v[j] = (short)bf16bits(f);
            }
            wb[s] = v;
        }
        const int nl = ng & 63;
        #pragma unroll
        for (int s = 0; s < 4; s++) {
            short8 v;
            #pragma unroll
            for (int j = 0; j < 8; j++) {
                int k = 32 * s + quad * 8 + j;
                float f = head ? c_w1[k * Hn + nl] : n_w1[k * Hn + nl];
                v[j] = (short)bf16bits(f);
            }
            w1b[s] = v;
        }
        #pragma unroll
        for (int r = 0; r < 4; r++)
            cbias[r] = conv_b[wave * 16 + 4 * quad + r];
        b1v = head ? c_b1[nl] : n_b1[nl];
        w2v = head ? c_w2[nl] : n_w2[nl];
    }
    const int plen_lane = plen_arr[b0 + col];   // this lane's batch (=col) plen

    __syncthreads();   // zero-init done before data fill

    // ---- stage seq -> bf16 LDS, rows shifted +4 (SAME pad), c<21 only ----
    // float4 global loads (11760 f32 / block contiguous). Element (bi,l,c) lives at
    // bi*1064 + (4+l)*24 + c. For a float4 starting at r = l*21+c, element j:
    //   row wrap  (c+j>=21):  next l row starts +24 vs +21 linear -> addr += 3
    //   batch wrap(r+j>=735): jump (bi,34,20)->(bi+1,0,0): addr += 224 more (=227 total)
    {
        const float4* gsrc = (const float4*)(seq + (size_t)b0 * (Ln * CINn));
        for (int i = t; i < (GB * Ln * CINn) / 4; i += 512) {
            int i4 = i * 4;
            int bi = i4 / (Ln * CINn), r = i4 - bi * (Ln * CINn);
            int l = r / CINn, c = r - l * CINn;
            float4 v = gsrc[i];
            int base = bi * SEQ_STRIDE + (4 + l) * CINP + c;
            #pragma unroll
            for (int j = 0; j < 4; j++) {
                float fj = (j == 0) ? v.x : (j == 1) ? v.y : (j == 2) ? v.z : v.w;
                int adj = ((c + j >= CINn) ? 3 : 0) + ((r + j >= Ln * CINn) ? 224 : 0);
                s_seq[base + j + adj] = bf16bits(fj);
            }
        }
    }
    __syncthreads();

    float sum_n[4] = {0.f,0.f,0.f,0.f};
    float sum_c[4] = {0.f,0.f,0.f,0.f};

    // ---- main loop: 2 l per stage, 18 stages. MLP section (2 barriers) only in the
    // 8 stages with l0 in [10,26). 2-slot ring on s_tile (slot = l&1): write {0,1} ->
    // barrier -> read -> barrier -> next write. l=35 = computed pad (auto-masked).
    for (int l0 = 0; l0 < 36; l0 += 2) {
        const int l1 = l0 + 1;
        // ---- conv GEMM (operand-swapped): D^T[f][batch], wave's 16-f tile ----
        short8 af0[7], af1[7];
        #pragma unroll
        for (int s = 0; s < 7; s++) {
            af0[s] = *(const short8*)&s_seq[col * SEQ_STRIDE + l0 * CINP + 32 * s + quad * 8];
            af1[s] = *(const short8*)&s_seq[col * SEQ_STRIDE + l1 * CINP + 32 * s + quad * 8];
        }
        f32x4 cacc0 = {0.f,0.f,0.f,0.f};
        f32x4 cacc1 = {0.f,0.f,0.f,0.f};
        #pragma unroll
        for (int s = 0; s < 7; s++) {
            cacc0 = __builtin_amdgcn_mfma_f32_16x16x32_bf16(wb[s], af0[s], cacc0, 0, 0, 0);
            cacc1 = __builtin_amdgcn_mfma_f32_16x16x32_bf16(wb[s], af1[s], cacc1, 0, 0, 0);
        }
        // ---- epilogue: lane holds batch=col, f = 16*wave + 4q + r ----
        float a0 = fmaxf(cacc0[0] + cbias[0], 0.0f);
        float a1 = fmaxf(cacc0[1] + cbias[1], 0.0f);
        float a2 = fmaxf(cacc0[2] + cbias[2], 0.0f);
        float a3 = fmaxf(cacc0[3] + cbias[3], 0.0f);
        float e0 = fmaxf(cacc1[0] + cbias[0], 0.0f);
        float e1 = fmaxf(cacc1[1] + cbias[1], 0.0f);
        float e2 = fmaxf(cacc1[2] + cbias[2], 0.0f);
        float e3 = fmaxf(cacc1[3] + cbias[3], 0.0f);
        {
            float cm0 = (l0 >= 10 + plen_lane && l0 < 20 + plen_lane) ? 1.0f : 0.0f;
            float cm1 = (l1 >= 10 + plen_lane && l1 < 20 + plen_lane) ? 1.0f : 0.0f;
            if (l0 < 10) {            // wave-uniform
                sum_n[0] += a0; sum_n[1] += a1; sum_n[2] += a2; sum_n[3] += a3;
            }
            if (l1 < 10) {
                sum_n[0] += e0; sum_n[1] += e1; sum_n[2] += e2; sum_n[3] += e3;
            }
            sum_c[0] += cm0 * a0 + cm1 * e0;
            sum_c[1] += cm0 * a1 + cm1 * e1;
            sum_c[2] += cm0 * a2 + cm1 * e2;
            sum_c[3] += cm0 * a3 + cm1 * e3;
        }

        // ---- MLP section: only for l whose y is consumed (l in [10,25]) ----
        if (l0 >= 10 && l0 < 26) {           // block-uniform; barriers inside are legal
            ushort4 pk0 = { bf16bits(a0), bf16bits(a1), bf16bits(a2), bf16bits(a3) };
            ushort4 pk1 = { bf16bits(e0), bf16bits(e1), bf16bits(e2), bf16bits(e3) };
            *(ushort4*)&s_tile[0][col * TILE_STRIDE + wave * 16 + 4 * quad] = pk0;
            *(ushort4*)&s_tile[1][col * TILE_STRIDE + wave * 16 + 4 * quad] = pk1;
            __syncthreads();   // conv tiles written -> MLP may read

            // ---- MLP layer1 GEMM: D[m=batch][n = wave's 16-n tile], K = 128 f ----
            short8 am0[4], am1[4];
            #pragma unroll
            for (int s = 0; s < 4; s++) {
                am0[s] = *(const short8*)&s_tile[0][col * TILE_STRIDE + 32 * s + quad * 8];
                am1[s] = *(const short8*)&s_tile[1][col * TILE_STRIDE + 32 * s + quad * 8];
            }
            f32x4 hacc0 = {0.f,0.f,0.f,0.f};
            f32x4 hacc1 = {0.f,0.f,0.f,0.f};
            #pragma unroll
            for (int s = 0; s < 4; s++) {
                hacc0 = __builtin_amdgcn_mfma_f32_16x16x32_bf16(am0[s], w1b[s], hacc0, 0, 0, 0);
                hacc1 = __builtin_amdgcn_mfma_f32_16x16x32_bf16(am1[s], w1b[s], hacc1, 0, 0, 0);
            }
            // ---- y partial = relu(h+b1) @ w2 over this wave's 16 n; DPP row-sum ----
            float p0[4], p1[4];
            #pragma unroll
            for (int r = 0; r < 4; r++) {
                p0[r] = row_sum16(fmaxf(hacc0[r] + b1v, 0.f) * w2v);
                p1[r] = row_sum16(fmaxf(hacc1[r] + b1v, 0.f) * w2v);
            }
            if (col == 0) {                  // batch index = 4*quad + r
                *(f32x4*)&s_yp[(l0 - 10) * YP_STRIDE + wave * 16 + quad * 4] =
                    (f32x4){p0[0], p0[1], p0[2], p0[3]};
                *(f32x4*)&s_yp[(l1 - 10) * YP_STRIDE + wave * 16 + quad * 4] =
                    (f32x4){p1[0], p1[1], p1[2], p1[3]};
            }
            __syncthreads();   // MLP reads done -> next stage may rewrite slots (2-slot WAR)
        }
    }
    __syncthreads();   // all s_seq reads done -> overlay safe; s_yp complete

    // ---- flank-average partials: apply navg_w/cavg_w post-loop ----
    {
        float an = 0.f, ac = 0.f;
        #pragma unroll
        for (int r = 0; r < 4; r++) {
            int fidx = wave * 16 + 4 * quad + r;
            an += sum_n[r] * navg_w[fidx];
            ac += sum_c[r] * cavg_w[fidx];
        }
        an += __shfl_xor(an, 16); an += __shfl_xor(an, 32);   // sum over quads
        ac += __shfl_xor(ac, 16); ac += __shfl_xor(ac, 32);
        if (quad == 0) {                     // lane < 16: one per batch
            s_avg[wave * 2 * GB + 0 * GB + col] = an;
            s_avg[wave * 2 * GB + 1 * GB + col] = ac;
        }
    }
    __syncthreads();

    // ---- y finalize: y = tanh(sum of 4 wave-partials + b2), l in [10,25] (512 vals) ----
    // m-fastest decomposition: 64 lanes cover all 32 banks 2-way (conflict-free);
    // YP_STRIDE=136 decorrelates the per-l bank offset (136%32 = 8).
    {
        const float bn = n_b2[0], bc = c_b2[0];
        for (int i = t; i < 2 * GB * NYL; i += 512) {
            int m = i & 15, rem = i >> 4;        // rem = 0..31
            int li = rem & 15, hd = rem >> 4;    // li = l-10
            float v = (hd ? bc : bn);
            #pragma unroll
            for (int w = 0; w < 4; w++)
                v += s_yp[li * YP_STRIDE + (hd * 4 + w) * 16 + m];
            s_y[hd * GB * 36 + m * 36 + (10 + li)] = tanhf(v);
        }
    }
    __syncthreads();

    // ---- final combine: one thread per batch row ----
    if (t < GB) {
        const int m = t;
        const int plen = plen_arr[b0 + m];
        const float* ym = s_y + m * 36;               // n-head row
        const float* yc = s_y + GB * 36 + m * 36;     // c-head row
        float cleaved_n = ym[10];
        float mn = 0.f;   // reference maxes (y+1)*mask over ALL l; unmasked give 0
        for (int l = 11; l < 10 + plen; l++) mn = fmaxf(mn, ym[l] + 1.f);
        float maxpool_n = -(mn - 1.f);
        float cleaved_c = yc[10 + plen - 1];
        float mc = 0.f;
        for (int l = 10; l < 10 + plen - 1; l++) mc = fmaxf(mc, yc[l] + 1.f);
        float maxpool_c = -(mc - 1.f);
        float sn = 0.f, sc = 0.f;
        #pragma unroll
        for (int w = 0; w < 8; w++) {
            sn += s_avg[w * 2 * GB + 0 * GB + m];
            sc += s_avg[w * 2 * GB + 1 * GB + m];
        }
        float avg_n = tanhf(sn * 0.1f + navg_b[0]);
        float avg_c = tanhf(sc * 0.1f + cavg_b[0]);
        float comb = cleaved_n * out_w[0] + maxpool_n * out_w[1] + avg_n * out_w[2]
                   + cleaved_c * out_w[3] + maxpool_c * out_w[4] + avg_c * out_w[5]
                   + out_b[0];
        out[b0 + m] = 1.f / (1.f + expf(-comb));
    }
}

extern "C" void kernel_launch(void* const* d_in, const int* in_sizes, int n_in,
                              void* d_out, int out_size, void* d_ws, size_t ws_size,
                              hipStream_t stream) {
    const int B = in_sizes[1];
    fused_kernel<<<B / GB, 512, 0, stream>>>(
        (const float*)d_in[0],  (const int*)d_in[1],
        (const float*)d_in[2],  (const float*)d_in[3],
        (const float*)d_in[4],  (const float*)d_in[5],
        (const float*)d_in[6],  (const float*)d_in[7],
        (const float*)d_in[8],  (const float*)d_in[9],
        (const float*)d_in[10], (const float*)d_in[11],
        (const float*)d_in[12], (const float*)d_in[13],
        (const float*)d_in[14], (const float*)d_in[15],
        (const float*)d_in[16], (const float*)d_in[17],
        (float*)d_out);
}